// Round 7
// baseline (294.566 us; speedup 1.0000x reference)
//
#include <hip/hip_runtime.h>

#define N_TOK 8192
#define D_DIM 1024
#define H_DIM 2048
#define E_NUM 8
#define CAP   1280

typedef __attribute__((ext_vector_type(8))) short bf16x8;
typedef __attribute__((ext_vector_type(4))) float f32x4;

__device__ inline unsigned short f2bf(float f) {
  unsigned u = __float_as_uint(f);
  u += 0x7fffu + ((u >> 16) & 1u);
  return (unsigned short)(u >> 16);
}

__device__ inline void vm_drain() {
  asm volatile("s_waitcnt vmcnt(0)" ::: "memory");
}

// ---------------- transpose+convert to FRAGMENT-MAJOR bf16:
// src (b, R, C) f32  [R = K rows, C = N cols]
// dst (b, C/16, R/8, 16, 8) bf16 : element (r,c) -> ((c>>4)*(R/8)+(r>>3))*128 + (c&15)*8 + (r&7)
// One MFMA B-fragment (16 n-cols x 8 k) = 128 contiguous elems; a wave's 4-chunk
// fragment load = 1KB contiguous -> perfectly coalesced global_load_dwordx4.
__global__ __launch_bounds__(256) void transpose_cvt_frag(const float* __restrict__ src,
                                                          unsigned short* __restrict__ dst,
                                                          int R, int C) {
  __shared__ float tile[64][33];
  const int b = blockIdx.z;
  src += (size_t)b * R * C;
  dst += (size_t)b * R * C;
  const int c0 = blockIdx.x * 32, r0 = blockIdx.y * 64;
  const int tx = threadIdx.x & 31, ty = threadIdx.x >> 5;  // 256 = (32,8)
#pragma unroll
  for (int i = 0; i < 8; ++i)
    tile[ty + i * 8][tx] = src[(size_t)(r0 + ty + i * 8) * C + c0 + tx];
  __syncthreads();
  const int c = threadIdx.x & 31;   // col within tile
  const int ro = threadIdx.x >> 5;  // row-oct 0..7
  unsigned short v[8];
#pragma unroll
  for (int i = 0; i < 8; ++i) v[i] = f2bf(tile[ro * 8 + i][c]);
  const int gc = c0 + c;
  const size_t off = ((size_t)(gc >> 4) * (R >> 3) + (r0 >> 3) + ro) * 128 + (gc & 15) * 8;
  *reinterpret_cast<bf16x8*>(dst + off) = *reinterpret_cast<const bf16x8*>(v);
}

// ---------------- gating
__global__ __launch_bounds__(256) void gate_kernel(const float* __restrict__ x,
                                                   const float* __restrict__ Wg,
                                                   const float* __restrict__ bg,
                                                   int* __restrict__ eid,
                                                   float* __restrict__ gatew) {
  __shared__ float wg[E_NUM][D_DIM];
  const int tid = threadIdx.x;
  for (int i = tid; i < D_DIM * E_NUM; i += 256) {
    int d = i >> 3, e = i & 7;
    wg[e][d] = Wg[i];
  }
  __syncthreads();
  const int w = tid >> 6, l = tid & 63;
  const int t = blockIdx.x * 4 + w;
  const float* xr = x + (size_t)t * D_DIM;
  float acc[8] = {0, 0, 0, 0, 0, 0, 0, 0};
#pragma unroll
  for (int i = 0; i < D_DIM / 64; ++i) {
    float xv = xr[l + 64 * i];
#pragma unroll
    for (int e = 0; e < 8; ++e) acc[e] += xv * wg[e][l + 64 * i];
  }
#pragma unroll
  for (int off = 32; off >= 1; off >>= 1) {
#pragma unroll
    for (int e = 0; e < 8; ++e) acc[e] += __shfl_xor(acc[e], off);
  }
  if (l == 0) {
    float best = -1e30f;
    int bi = 0;
#pragma unroll
    for (int e = 0; e < 8; ++e) {
      acc[e] += bg[e];
      if (acc[e] > best) { best = acc[e]; bi = e; }
    }
    float s = 0.f;
#pragma unroll
    for (int e = 0; e < 8; ++e) s += __expf(acc[e] - best);
    eid[t] = bi;
    gatew[t] = 1.f / s;
  }
}

// ---------------- sequential (stable) per-expert position scan, single wave
__global__ void scan_kernel(const int* __restrict__ eid, int* __restrict__ slot,
                            int* __restrict__ tok_of) {
  __shared__ int se[N_TOK];
  const int tid = threadIdx.x;  // 256
  for (int i = tid; i < N_TOK; i += 256) se[i] = eid[i];
  __syncthreads();
  if (tid >= 64) return;
  int counts[8] = {0, 0, 0, 0, 0, 0, 0, 0};
  const unsigned long long lower = (tid == 0) ? 0ull : ((1ull << tid) - 1ull);
  for (int base = 0; base < N_TOK; base += 64) {
    const int t = base + tid;
    const int e = se[t];
    int rank = 0;
#pragma unroll
    for (int ee = 0; ee < 8; ++ee) {
      unsigned long long m = __ballot(e == ee);
      if (e == ee) rank = counts[ee] + __popcll(m & lower);
      counts[ee] += __popcll(m);
    }
    slot[t] = rank < CAP ? rank : CAP;
    if (rank < CAP) tok_of[e * CAP + rank] = t;
  }
}

// ---------------- scatter x rows -> binp (E,CAP,D) bf16; empty rows = 0
__global__ __launch_bounds__(256) void scatter_kernel(const float* __restrict__ x,
                                                      const int* __restrict__ tok_of,
                                                      unsigned short* __restrict__ binp) {
  const int row = blockIdx.x * 4 + (threadIdx.x >> 6);
  const int l = threadIdx.x & 63;
  const int t = tok_of[row];
  unsigned short* dst = binp + (size_t)row * D_DIM;
  if (t >= 0) {
    const float* src = x + (size_t)t * D_DIM;
#pragma unroll
    for (int i = 0; i < 4; ++i) {
      const int d = (i * 64 + l) * 4;
      float4 v = *reinterpret_cast<const float4*>(src + d);
      unsigned short r[4] = {f2bf(v.x), f2bf(v.y), f2bf(v.z), f2bf(v.w)};
      *reinterpret_cast<uint2*>(dst + d) = *reinterpret_cast<uint2*>(r);
    }
  } else {
    uint2 z = {0u, 0u};
#pragma unroll
    for (int i = 0; i < 4; ++i) {
      const int d = (i * 64 + l) * 4;
      *reinterpret_cast<uint2*>(dst + d) = z;
    }
  }
}

// ================= A-tile staging, 128x64 bf16 (R4-proven, 0 conflicts) =====
#define TILE64 (128 * 64)

// 4-wave version: wave w stages rows w*32..w*32+31
__device__ inline void stage_tile4(const unsigned short* __restrict__ g, int ldg, int k0,
                                   unsigned short* lds, int w, int l) {
  const int gcol = (l & 7) ^ (l >> 3);
  const unsigned short* gsrc = g + (size_t)(w * 32 + (l >> 3)) * ldg + k0 + gcol * 8;
#pragma unroll
  for (int it = 0; it < 4; ++it) {
    __builtin_amdgcn_global_load_lds(
        (const __attribute__((address_space(1))) unsigned int*)(gsrc + (size_t)(it * 8) * ldg),
        (__attribute__((address_space(3))) unsigned int*)(lds + (w * 32 + it * 8) * 64),
        16, 0, 0);
  }
}

// 2-wave version: wave w stages rows w*64..w*64+63
__device__ inline void stage_tile2(const unsigned short* __restrict__ g, int ldg, int k0,
                                   unsigned short* lds, int w, int l) {
  const int gcol = (l & 7) ^ (l >> 3);
  const unsigned short* gsrc = g + (size_t)(w * 64 + (l >> 3)) * ldg + k0 + gcol * 8;
#pragma unroll
  for (int it = 0; it < 8; ++it) {
    __builtin_amdgcn_global_load_lds(
        (const __attribute__((address_space(1))) unsigned int*)(gsrc + (size_t)(it * 8) * ldg),
        (__attribute__((address_space(3))) unsigned int*)(lds + (w * 64 + it * 8) * 64),
        16, 0, 0);
  }
}

__device__ inline bf16x8 lds_frag(const unsigned short* lds, int row, int c16) {
  return *reinterpret_cast<const bf16x8*>(lds + row * 64 + (c16 ^ (row & 7)) * 8);
}

// B-fragment direct from frag-major weights: n16 = 16-col block, kcb = k-chunk base,
// KD8 = K/8. Wave load = 1KB contiguous.
__device__ inline bf16x8 gfrag(const unsigned short* __restrict__ wf, int n16, int kcb,
                               int KD8, int l) {
  return *reinterpret_cast<const bf16x8*>(
      wf + ((size_t)n16 * KD8 + kcb + (l >> 4)) * 128 + (l & 15) * 8);
}

// ---------------- ffn1: h = silu(X@W2)*(X@W3). grid (H/128, CAP/128, E), 256 thr.
// A (tokens) in LDS double-buffered; W2/W3 fragments direct from global (L2).
__global__ __launch_bounds__(256, 2) void ffn1_kernel(const unsigned short* __restrict__ binp,
                                                      const unsigned short* __restrict__ w2f,
                                                      const unsigned short* __restrict__ w3f,
                                                      unsigned short* __restrict__ hbuf) {
  __shared__ unsigned short sA[2][TILE64];  // 32 KB
  const int e = blockIdx.z, bx = blockIdx.x, by = blockIdx.y;
  const unsigned short* A = binp + (size_t)e * CAP * D_DIM + (size_t)by * 128 * D_DIM;
  const unsigned short* B2 = w2f + (size_t)e * H_DIM * D_DIM;
  const unsigned short* B3 = w3f + (size_t)e * H_DIM * D_DIM;
  unsigned short* H = hbuf + (size_t)e * CAP * H_DIM;
  const int tid = threadIdx.x;
  const int l = tid & 63;
  const int w = tid >> 6, wr = w >> 1, wc = w & 1;
  const int h16w = bx * 8 + wc * 4;  // wave's 16-col block base in H
  f32x4 acc2[4][4] = {};
  f32x4 acc3[4][4] = {};

  stage_tile4(A, D_DIM, 0, sA[0], w, l);
  vm_drain();
  __syncthreads();

  const int NT = D_DIM / 64;  // 16
  int cur = 0;
  for (int kt = 0; kt < NT; ++kt) {
    const int nxt = cur ^ 1;
    // B fragments for both K=32 halves, issued FIRST (oldest in vmcnt queue ->
    // MFMA's wait does not chain behind the A prefetch issued after).
    bf16x8 b2[2][4], b3[2][4];
#pragma unroll
    for (int kk = 0; kk < 2; ++kk)
#pragma unroll
      for (int f = 0; f < 4; ++f) {
        b2[kk][f] = gfrag(B2, h16w + f, kt * 8 + kk * 4, D_DIM / 8, l);
        b3[kk][f] = gfrag(B3, h16w + f, kt * 8 + kk * 4, D_DIM / 8, l);
      }
    if (kt + 1 < NT) stage_tile4(A, D_DIM, (kt + 1) * 64, sA[nxt], w, l);
#pragma unroll
    for (int kk = 0; kk < 2; ++kk) {
      const int c16 = kk * 4 + (l >> 4);
      bf16x8 af[4];
#pragma unroll
      for (int f = 0; f < 4; ++f)
        af[f] = lds_frag(sA[cur], wr * 64 + f * 16 + (l & 15), c16);
#pragma unroll
      for (int fm = 0; fm < 4; ++fm)
#pragma unroll
        for (int fn = 0; fn < 4; ++fn) {
          acc2[fm][fn] = __builtin_amdgcn_mfma_f32_16x16x32_bf16(af[fm], b2[kk][fn], acc2[fm][fn], 0, 0, 0);
          acc3[fm][fn] = __builtin_amdgcn_mfma_f32_16x16x32_bf16(af[fm], b3[kk][fn], acc3[fm][fn], 0, 0, 0);
        }
    }
    vm_drain();       // only the A prefetch remains outstanding here
    __syncthreads();
    cur = nxt;
  }

  const int row0 = by * 128 + wr * 64;
  const int col0 = bx * 128 + wc * 64;
#pragma unroll
  for (int fm = 0; fm < 4; ++fm)
#pragma unroll
    for (int fn = 0; fn < 4; ++fn)
#pragma unroll
      for (int j = 0; j < 4; ++j) {
        const int row = row0 + fm * 16 + (l >> 4) * 4 + j;
        const int col = col0 + fn * 16 + (l & 15);
        const float v2 = acc2[fm][fn][j];
        const float v3 = acc3[fm][fn][j];
        const float hv = (v2 / (1.0f + __expf(-v2))) * v3;
        H[(size_t)row * H_DIM + col] = f2bf(hv);
      }
}

// ---------------- ffn2: out[t] = gate[t]*(h@W1). grid (D/128, CAP/128, E), 128 thr.
// 2 waves, wave tile 64 rows x 128 cols (acc[4][8]); W1 fragments direct.
__global__ __launch_bounds__(128, 2) void ffn2_kernel(const unsigned short* __restrict__ hbuf,
                                                      const unsigned short* __restrict__ w1f,
                                                      const int* __restrict__ tok_of,
                                                      const float* __restrict__ gatew,
                                                      float* __restrict__ out) {
  __shared__ unsigned short sA[2][TILE64];  // 32 KB
  const int e = blockIdx.z, bx = blockIdx.x, by = blockIdx.y;
  const unsigned short* A = hbuf + (size_t)e * CAP * H_DIM + (size_t)by * 128 * H_DIM;
  const unsigned short* B = w1f + (size_t)e * D_DIM * H_DIM;
  const int* tok = tok_of + e * CAP;
  const int tid = threadIdx.x;
  const int l = tid & 63;
  const int w = tid >> 6;            // 0..1, wave's 64-row half
  const int d16w = bx * 8;           // block's 16-col base in D (8 blocks of 16 = 128 cols)
  f32x4 acc[4][8] = {};

  stage_tile2(A, H_DIM, 0, sA[0], w, l);
  vm_drain();
  __syncthreads();

  const int NT = H_DIM / 64;  // 32
  int cur = 0;
  for (int kt = 0; kt < NT; ++kt) {
    const int nxt = cur ^ 1;
    bf16x8 bfr[2][8];
#pragma unroll
    for (int kk = 0; kk < 2; ++kk)
#pragma unroll
      for (int fn = 0; fn < 8; ++fn)
        bfr[kk][fn] = gfrag(B, d16w + fn, kt * 8 + kk * 4, H_DIM / 8, l);
    if (kt + 1 < NT) stage_tile2(A, H_DIM, (kt + 1) * 64, sA[nxt], w, l);
#pragma unroll
    for (int kk = 0; kk < 2; ++kk) {
      const int c16 = kk * 4 + (l >> 4);
      bf16x8 af[4];
#pragma unroll
      for (int f = 0; f < 4; ++f)
        af[f] = lds_frag(sA[cur], w * 64 + f * 16 + (l & 15), c16);
#pragma unroll
      for (int fm = 0; fm < 4; ++fm)
#pragma unroll
        for (int fn = 0; fn < 8; ++fn)
          acc[fm][fn] = __builtin_amdgcn_mfma_f32_16x16x32_bf16(af[fm], bfr[kk][fn], acc[fm][fn], 0, 0, 0);
    }
    vm_drain();
    __syncthreads();
    cur = nxt;
  }

  const int row0 = by * 128 + w * 64;
  const int col0 = bx * 128;
#pragma unroll
  for (int fm = 0; fm < 4; ++fm)
#pragma unroll
    for (int j = 0; j < 4; ++j) {
      const int row = row0 + fm * 16 + (l >> 4) * 4 + j;
      const int t = tok[row];
      if (t >= 0) {
        const float g = gatew[t];
#pragma unroll
        for (int fn = 0; fn < 8; ++fn) {
          const int col = col0 + fn * 16 + (l & 15);
          out[(size_t)t * D_DIM + col] = g * acc[fm][fn][j];
        }
      }
    }
}

// ---------------- overflow tokens (slot >= CAP) -> out = 0
__global__ __launch_bounds__(256) void zero_overflow(const int* __restrict__ slot,
                                                     float* __restrict__ out) {
  const int t = blockIdx.x * 4 + (threadIdx.x >> 6);
  if (slot[t] < CAP) return;
  const int l = threadIdx.x & 63;
  float4 z = {0.f, 0.f, 0.f, 0.f};
#pragma unroll
  for (int i = 0; i < 4; ++i)
    *reinterpret_cast<float4*>(out + (size_t)t * D_DIM + (i * 64 + l) * 4) = z;
}

extern "C" void kernel_launch(void* const* d_in, const int* in_sizes, int n_in,
                              void* d_out, int out_size, void* d_ws, size_t ws_size,
                              hipStream_t stream) {
  const float* x  = (const float*)d_in[0];
  const float* Wg = (const float*)d_in[1];
  const float* bg = (const float*)d_in[2];
  const float* W1 = (const float*)d_in[3];
  const float* W2 = (const float*)d_in[4];
  const float* W3 = (const float*)d_in[5];
  float* out = (float*)d_out;

  char* ws = (char*)d_ws;
  unsigned short* w2f = (unsigned short*)ws; ws += (size_t)E_NUM * H_DIM * D_DIM * 2;
  unsigned short* w3f = (unsigned short*)ws; ws += (size_t)E_NUM * H_DIM * D_DIM * 2;
  unsigned short* w1f = (unsigned short*)ws; ws += (size_t)E_NUM * D_DIM * H_DIM * 2;
  unsigned short* binp = (unsigned short*)ws; ws += (size_t)E_NUM * CAP * D_DIM * 2;
  unsigned short* hbuf = (unsigned short*)ws; ws += (size_t)E_NUM * CAP * H_DIM * 2;
  int* eid = (int*)ws;    ws += (size_t)N_TOK * 4;
  float* gw = (float*)ws; ws += (size_t)N_TOK * 4;
  int* slot = (int*)ws;   ws += (size_t)N_TOK * 4;
  int* tok_of = (int*)ws; ws += (size_t)E_NUM * CAP * 4;

  dim3 tb(256);
  // W2 (E,D,H): K=D rows, N=H cols -> frag-major
  transpose_cvt_frag<<<dim3(H_DIM / 32, D_DIM / 64, E_NUM), tb, 0, stream>>>(W2, w2f, D_DIM, H_DIM);
  transpose_cvt_frag<<<dim3(H_DIM / 32, D_DIM / 64, E_NUM), tb, 0, stream>>>(W3, w3f, D_DIM, H_DIM);
  // W1 (E,H,D): K=H rows, N=D cols
  transpose_cvt_frag<<<dim3(D_DIM / 32, H_DIM / 64, E_NUM), tb, 0, stream>>>(W1, w1f, H_DIM, D_DIM);

  hipMemsetAsync(tok_of, 0xFF, (size_t)E_NUM * CAP * 4, stream);  // tok_of = -1
  gate_kernel<<<N_TOK / 4, 256, 0, stream>>>(x, Wg, bg, eid, gw);
  scan_kernel<<<1, 256, 0, stream>>>(eid, slot, tok_of);
  scatter_kernel<<<E_NUM * CAP / 4, 256, 0, stream>>>(x, tok_of, binp);
  ffn1_kernel<<<dim3(H_DIM / 128, CAP / 128, E_NUM), 256, 0, stream>>>(binp, w2f, w3f, hbuf);
  ffn2_kernel<<<dim3(D_DIM / 128, CAP / 128, E_NUM), 128, 0, stream>>>(hbuf, w1f, tok_of, gw, out);
  zero_overflow<<<N_TOK / 4, 256, 0, stream>>>(slot, out);
}

// Round 8
// 264.884 us; speedup vs baseline: 1.1121x; 1.1121x over previous
//
#include <hip/hip_runtime.h>

#define N_TOK 8192
#define D_DIM 1024
#define H_DIM 2048
#define E_NUM 8
#define CAP   1280

typedef __attribute__((ext_vector_type(8))) short bf16x8;
typedef __attribute__((ext_vector_type(4))) float f32x4;

__device__ inline unsigned short f2bf(float f) {
  unsigned u = __float_as_uint(f);
  u += 0x7fffu + ((u >> 16) & 1u);
  return (unsigned short)(u >> 16);
}

// Counted vmcnt wait + raw barrier (NO __syncthreads in the hot loop: it forces
// a full vmcnt(0) drain before s_barrier, serializing the A-prefetch).
#define VMCNT(n) asm volatile("s_waitcnt vmcnt(" #n ")" ::: "memory")
#define BARRIER() asm volatile("s_barrier" ::: "memory")

// ---------------- merged transpose + fp32->bf16 for all three weights
// src (b,R,C) f32 -> dst (b,C,R) bf16.  1-D grid, 3 x 8192 blocks.
__global__ __launch_bounds__(256) void transpose_cvt_all(const float* __restrict__ W2,
                                                         const float* __restrict__ W3,
                                                         const float* __restrict__ W1,
                                                         unsigned short* __restrict__ w2t,
                                                         unsigned short* __restrict__ w3t,
                                                         unsigned short* __restrict__ w1t) {
  __shared__ float tile[64][33];
  const int id = blockIdx.x;
  const float* src;
  unsigned short* dst;
  int R, C, bx, by, b;
  if (id < 16384) {  // W2 / W3: R=D=1024, C=H=2048; per-b grid 64 x 16
    const int q = id & 8191;
    b = q >> 10;                 // q / 1024
    const int rem = q & 1023;
    bx = rem & 63;
    by = rem >> 6;
    R = D_DIM; C = H_DIM;
    src = (id < 8192 ? W2 : W3);
    dst = (id < 8192 ? w2t : w3t);
  } else {           // W1: R=H=2048, C=D=1024; per-b grid 32 x 32
    const int q = id - 16384;
    b = q >> 10;
    const int rem = q & 1023;
    bx = rem & 31;
    by = rem >> 5;
    R = H_DIM; C = D_DIM;
    src = W1; dst = w1t;
  }
  src += (size_t)b * R * C;
  dst += (size_t)b * R * C;
  const int c0 = bx * 32, r0 = by * 64;
  const int tx = threadIdx.x & 31, ty = threadIdx.x >> 5;
#pragma unroll
  for (int i = 0; i < 8; ++i)
    tile[ty + i * 8][tx] = src[(size_t)(r0 + ty + i * 8) * C + c0 + tx];
  __syncthreads();
  const int rp = threadIdx.x & 31;
  const int cb = threadIdx.x >> 5;
#pragma unroll
  for (int it = 0; it < 4; ++it) {
    const int c = cb + it * 8;
    unsigned short v[2] = {f2bf(tile[2 * rp][c]), f2bf(tile[2 * rp + 1][c])};
    *reinterpret_cast<unsigned*>(dst + (size_t)(c0 + c) * R + r0 + 2 * rp) =
        *reinterpret_cast<unsigned*>(v);
  }
}

// ---------------- gating: logits = x@Wg + bg; eid=argmax; gate = softmax(logits)[eid]
__global__ __launch_bounds__(256) void gate_kernel(const float* __restrict__ x,
                                                   const float* __restrict__ Wg,
                                                   const float* __restrict__ bg,
                                                   int* __restrict__ eid,
                                                   float* __restrict__ gatew) {
  __shared__ float wg[E_NUM][D_DIM];
  const int tid = threadIdx.x;
  for (int i = tid; i < D_DIM * E_NUM; i += 256) {
    int d = i >> 3, e = i & 7;
    wg[e][d] = Wg[i];
  }
  __syncthreads();
  const int w = tid >> 6, l = tid & 63;
  const int t = blockIdx.x * 4 + w;
  const float* xr = x + (size_t)t * D_DIM;
  float acc[8] = {0, 0, 0, 0, 0, 0, 0, 0};
#pragma unroll
  for (int i = 0; i < D_DIM / 64; ++i) {
    float xv = xr[l + 64 * i];
#pragma unroll
    for (int e = 0; e < 8; ++e) acc[e] += xv * wg[e][l + 64 * i];
  }
#pragma unroll
  for (int off = 32; off >= 1; off >>= 1) {
#pragma unroll
    for (int e = 0; e < 8; ++e) acc[e] += __shfl_xor(acc[e], off);
  }
  if (l == 0) {
    float best = -1e30f;
    int bi = 0;
#pragma unroll
    for (int e = 0; e < 8; ++e) {
      acc[e] += bg[e];
      if (acc[e] > best) { best = acc[e]; bi = e; }
    }
    float s = 0.f;
#pragma unroll
    for (int e = 0; e < 8; ++e) s += __expf(acc[e] - best);
    eid[t] = bi;
    gatew[t] = 1.f / s;
  }
}

// ---------------- sequential (stable) per-expert position scan, single wave
__global__ void scan_kernel(const int* __restrict__ eid, int* __restrict__ slot,
                            int* __restrict__ tok_of) {
  __shared__ int se[N_TOK];
  const int tid = threadIdx.x;  // 256
  for (int i = tid; i < N_TOK; i += 256) se[i] = eid[i];
  __syncthreads();
  if (tid >= 64) return;
  int counts[8] = {0, 0, 0, 0, 0, 0, 0, 0};
  const unsigned long long lower = (tid == 0) ? 0ull : ((1ull << tid) - 1ull);
  for (int base = 0; base < N_TOK; base += 64) {
    const int t = base + tid;
    const int e = se[t];
    int rank = 0;
#pragma unroll
    for (int ee = 0; ee < 8; ++ee) {
      unsigned long long m = __ballot(e == ee);
      if (e == ee) rank = counts[ee] + __popcll(m & lower);
      counts[ee] += __popcll(m);
    }
    slot[t] = rank < CAP ? rank : CAP;
    if (rank < CAP) tok_of[e * CAP + rank] = t;
  }
}

// ---------------- scatter x rows -> binp (E,CAP,D) bf16; empty rows = 0
__global__ __launch_bounds__(256) void scatter_kernel(const float* __restrict__ x,
                                                      const int* __restrict__ tok_of,
                                                      unsigned short* __restrict__ binp) {
  const int row = blockIdx.x * 4 + (threadIdx.x >> 6);
  const int l = threadIdx.x & 63;
  const int t = tok_of[row];
  unsigned short* dst = binp + (size_t)row * D_DIM;
  if (t >= 0) {
    const float* src = x + (size_t)t * D_DIM;
#pragma unroll
    for (int i = 0; i < 4; ++i) {
      const int d = (i * 64 + l) * 4;
      float4 v = *reinterpret_cast<const float4*>(src + d);
      unsigned short r[4] = {f2bf(v.x), f2bf(v.y), f2bf(v.z), f2bf(v.w)};
      *reinterpret_cast<uint2*>(dst + d) = *reinterpret_cast<uint2*>(r);
    }
  } else {
    uint2 z = {0u, 0u};
#pragma unroll
    for (int i = 0; i < 4; ++i) {
      const int d = (i * 64 + l) * 4;
      *reinterpret_cast<uint2*>(dst + d) = z;
    }
  }
}

// ================= BK=64 staging (R4-proven, 0 conflicts) =================
// Tile 128x64 bf16 = 16 KB; rows = 8 chunks of 16B; swizzle chunk ^= (row&7),
// realized by pre-swizzling the GLOBAL source chunk per lane (rule #21).
#define TILE64 (128 * 64)

__device__ inline void stage_tile(const unsigned short* __restrict__ g, int ldg, int k0,
                                  unsigned short* lds, int w, int l) {
  const int gcol = (l & 7) ^ (l >> 3);
  const unsigned short* gsrc = g + (size_t)(w * 32 + (l >> 3)) * ldg + k0 + gcol * 8;
#pragma unroll
  for (int it = 0; it < 4; ++it) {
    __builtin_amdgcn_global_load_lds(
        (const __attribute__((address_space(1))) unsigned int*)(gsrc + (size_t)(it * 8) * ldg),
        (__attribute__((address_space(3))) unsigned int*)(lds + (w * 32 + it * 8) * 64),
        16, 0, 0);
  }
}

__device__ inline bf16x8 lds_frag(const unsigned short* lds, int row, int c16) {
  return *reinterpret_cast<const bf16x8*>(lds + row * 64 + (c16 ^ (row & 7)) * 8);
}

// ---------------- ffn1: h = silu(X@W2)*(X@W3). grid (H/128, CAP/128, E).
// A double-buffered (prefetch flies under MFMA, counted vmcnt); B2/B3 single-
// buffered (overwrite fenced by the post-compute barrier). Raw s_barrier only.
__global__ __launch_bounds__(256, 2) void ffn1_kernel(const unsigned short* __restrict__ binp,
                                                      const unsigned short* __restrict__ w2t,
                                                      const unsigned short* __restrict__ w3t,
                                                      unsigned short* __restrict__ hbuf) {
  __shared__ unsigned short sA[2][TILE64], sB2[TILE64], sB3[TILE64];  // 64 KB
  const int e = blockIdx.z, bx = blockIdx.x, by = blockIdx.y;
  const unsigned short* A  = binp + (size_t)e * CAP * D_DIM + (size_t)by * 128 * D_DIM;
  const unsigned short* B2 = w2t + (size_t)e * H_DIM * D_DIM + (size_t)bx * 128 * D_DIM;
  const unsigned short* B3 = w3t + (size_t)e * H_DIM * D_DIM + (size_t)bx * 128 * D_DIM;
  unsigned short* H = hbuf + (size_t)e * CAP * H_DIM;
  const int tid = threadIdx.x;
  const int l = tid & 63;
  const int w = tid >> 6, wr = w >> 1, wc = w & 1;
  f32x4 acc2[4][4] = {};
  f32x4 acc3[4][4] = {};

  stage_tile(A, D_DIM, 0, sA[0], w, l);  // A[0]; waited by first VMCNT below

  const int NT = D_DIM / 64;  // 16
  int cur = 0;
  for (int kt = 0; kt < NT; ++kt) {
    // B for THIS step (sB overwrite is safe: bottom barrier of prev iter passed)
    stage_tile(B2, D_DIM, kt * 64, sB2, w, l);
    stage_tile(B3, D_DIM, kt * 64, sB3, w, l);
    if (kt + 1 < NT) {
      stage_tile(A, D_DIM, (kt + 1) * 64, sA[cur ^ 1], w, l);
      VMCNT(4);  // A[kt]+B[kt] retired (in-order); A[kt+1] (newest 4) in flight
    } else {
      VMCNT(0);
    }
    BARRIER();   // staging visible to all waves
#pragma unroll
    for (int kk = 0; kk < 2; ++kk) {
      const int c16 = kk * 4 + (l >> 4);
      bf16x8 af[4], b2f[4], b3f[4];
#pragma unroll
      for (int f = 0; f < 4; ++f) {
        af[f]  = lds_frag(sA[cur], wr * 64 + f * 16 + (l & 15), c16);
        b2f[f] = lds_frag(sB2, wc * 64 + f * 16 + (l & 15), c16);
        b3f[f] = lds_frag(sB3, wc * 64 + f * 16 + (l & 15), c16);
      }
#pragma unroll
      for (int fm = 0; fm < 4; ++fm)
#pragma unroll
        for (int fn = 0; fn < 4; ++fn) {
          acc2[fm][fn] = __builtin_amdgcn_mfma_f32_16x16x32_bf16(af[fm], b2f[fn], acc2[fm][fn], 0, 0, 0);
          acc3[fm][fn] = __builtin_amdgcn_mfma_f32_16x16x32_bf16(af[fm], b3f[fn], acc3[fm][fn], 0, 0, 0);
        }
    }
    BARRIER();   // all waves done reading sB/sA[cur] before next overwrite
    cur ^= 1;
  }

  const int row0 = by * 128 + wr * 64;
  const int col0 = bx * 128 + wc * 64;
#pragma unroll
  for (int fm = 0; fm < 4; ++fm)
#pragma unroll
    for (int fn = 0; fn < 4; ++fn)
#pragma unroll
      for (int j = 0; j < 4; ++j) {
        const int row = row0 + fm * 16 + (l >> 4) * 4 + j;
        const int col = col0 + fn * 16 + (l & 15);
        const float v2 = acc2[fm][fn][j];
        const float v3 = acc3[fm][fn][j];
        const float hv = (v2 / (1.0f + __expf(-v2))) * v3;
        H[(size_t)row * H_DIM + col] = f2bf(hv);
      }
}

// ---------------- ffn2: out[t] = gate[t]*(h@W1). grid (D/128, CAP/128, E).
__global__ __launch_bounds__(256, 2) void ffn2_kernel(const unsigned short* __restrict__ hbuf,
                                                      const unsigned short* __restrict__ w1t,
                                                      const int* __restrict__ tok_of,
                                                      const float* __restrict__ gatew,
                                                      float* __restrict__ out) {
  __shared__ unsigned short sA[2][TILE64], sB[TILE64];  // 48 KB
  const int e = blockIdx.z;
  const unsigned short* A = hbuf + (size_t)e * CAP * H_DIM + (size_t)blockIdx.y * 128 * H_DIM;
  const unsigned short* B = w1t + (size_t)e * D_DIM * H_DIM + (size_t)blockIdx.x * 128 * H_DIM;
  const int* tok = tok_of + e * CAP;
  const int tid = threadIdx.x;
  const int l = tid & 63;
  const int w = tid >> 6, wr = w >> 1, wc = w & 1;
  f32x4 acc[4][4] = {};

  stage_tile(A, H_DIM, 0, sA[0], w, l);

  const int NT = H_DIM / 64;  // 32
  int cur = 0;
  for (int kt = 0; kt < NT; ++kt) {
    stage_tile(B, H_DIM, kt * 64, sB, w, l);
    if (kt + 1 < NT) {
      stage_tile(A, H_DIM, (kt + 1) * 64, sA[cur ^ 1], w, l);
      VMCNT(4);  // A[kt]+B[kt] retired; A[kt+1] in flight
    } else {
      VMCNT(0);
    }
    BARRIER();
#pragma unroll
    for (int kk = 0; kk < 2; ++kk) {
      const int c16 = kk * 4 + (l >> 4);
      bf16x8 af[4], bfr[4];
#pragma unroll
      for (int f = 0; f < 4; ++f) {
        af[f]  = lds_frag(sA[cur], wr * 64 + f * 16 + (l & 15), c16);
        bfr[f] = lds_frag(sB, wc * 64 + f * 16 + (l & 15), c16);
      }
#pragma unroll
      for (int fm = 0; fm < 4; ++fm)
#pragma unroll
        for (int fn = 0; fn < 4; ++fn)
          acc[fm][fn] = __builtin_amdgcn_mfma_f32_16x16x32_bf16(af[fm], bfr[fn], acc[fm][fn], 0, 0, 0);
    }
    BARRIER();
    cur ^= 1;
  }

  const int row0 = blockIdx.y * 128 + wr * 64;
  const int col0 = blockIdx.x * 128 + wc * 64;
#pragma unroll
  for (int fm = 0; fm < 4; ++fm)
#pragma unroll
    for (int j = 0; j < 4; ++j) {
      const int row = row0 + fm * 16 + (l >> 4) * 4 + j;
      const int t = tok[row];
      if (t >= 0) {
        const float g = gatew[t];
#pragma unroll
        for (int fn = 0; fn < 4; ++fn) {
          const int col = col0 + fn * 16 + (l & 15);
          out[(size_t)t * D_DIM + col] = g * acc[fm][fn][j];
        }
      }
    }
}

// ---------------- overflow tokens (slot >= CAP) -> out = 0
__global__ __launch_bounds__(256) void zero_overflow(const int* __restrict__ slot,
                                                     float* __restrict__ out) {
  const int t = blockIdx.x * 4 + (threadIdx.x >> 6);
  if (slot[t] < CAP) return;
  const int l = threadIdx.x & 63;
  float4 z = {0.f, 0.f, 0.f, 0.f};
#pragma unroll
  for (int i = 0; i < 4; ++i)
    *reinterpret_cast<float4*>(out + (size_t)t * D_DIM + (i * 64 + l) * 4) = z;
}

extern "C" void kernel_launch(void* const* d_in, const int* in_sizes, int n_in,
                              void* d_out, int out_size, void* d_ws, size_t ws_size,
                              hipStream_t stream) {
  const float* x  = (const float*)d_in[0];
  const float* Wg = (const float*)d_in[1];
  const float* bg = (const float*)d_in[2];
  const float* W1 = (const float*)d_in[3];
  const float* W2 = (const float*)d_in[4];
  const float* W3 = (const float*)d_in[5];
  float* out = (float*)d_out;

  char* ws = (char*)d_ws;
  unsigned short* w2t = (unsigned short*)ws; ws += (size_t)E_NUM * H_DIM * D_DIM * 2;
  unsigned short* w3t = (unsigned short*)ws; ws += (size_t)E_NUM * H_DIM * D_DIM * 2;
  unsigned short* w1t = (unsigned short*)ws; ws += (size_t)E_NUM * D_DIM * H_DIM * 2;
  unsigned short* binp = (unsigned short*)ws; ws += (size_t)E_NUM * CAP * D_DIM * 2;
  unsigned short* hbuf = (unsigned short*)ws; ws += (size_t)E_NUM * CAP * H_DIM * 2;
  int* eid = (int*)ws;    ws += (size_t)N_TOK * 4;
  float* gw = (float*)ws; ws += (size_t)N_TOK * 4;
  int* slot = (int*)ws;   ws += (size_t)N_TOK * 4;
  int* tok_of = (int*)ws; ws += (size_t)E_NUM * CAP * 4;

  transpose_cvt_all<<<24576, 256, 0, stream>>>(W2, W3, W1, w2t, w3t, w1t);
  hipMemsetAsync(tok_of, 0xFF, (size_t)E_NUM * CAP * 4, stream);  // tok_of = -1
  gate_kernel<<<N_TOK / 4, 256, 0, stream>>>(x, Wg, bg, eid, gw);
  scan_kernel<<<1, 256, 0, stream>>>(eid, slot, tok_of);
  scatter_kernel<<<E_NUM * CAP / 4, 256, 0, stream>>>(x, tok_of, binp);
  ffn1_kernel<<<dim3(H_DIM / 128, CAP / 128, E_NUM), 256, 0, stream>>>(binp, w2t, w3t, hbuf);
  ffn2_kernel<<<dim3(D_DIM / 128, CAP / 128, E_NUM), 256, 0, stream>>>(hbuf, w1t, tok_of, gw, out);
  zero_overflow<<<N_TOK / 4, 256, 0, stream>>>(slot, out);
}